// Round 1
// baseline (357.236 us; speedup 1.0000x reference)
//
#include <hip/hip_runtime.h>

// ROI Align (FPN multi-level), OUT=7, sampling ratio=2.
// One thread per output element (m, c, py, px). out layout [M][256][7][7],
// linear idx -> px fastest => coalesced stores. Reads: 16 gathers/thread,
// spatially local per (m,c) footprint (~14x14 feature px at assigned level).

#define NCH 256
#define POOL 7

__global__ __launch_bounds__(256) void roi_align_kernel(
    const float* __restrict__ f0, const float* __restrict__ f1,
    const float* __restrict__ f2, const float* __restrict__ f3,
    const float* __restrict__ boxes, const int* __restrict__ bidx,
    float* __restrict__ out, int M)
{
    int idx = blockIdx.x * 256 + threadIdx.x;
    int total = M * NCH * POOL * POOL;
    if (idx >= total) return;

    int px = idx % POOL;
    int py = (idx / POOL) % POOL;
    int c  = (idx / (POOL * POOL)) & (NCH - 1);
    int m  = idx / (POOL * POOL * NCH);

    float bx0 = boxes[4 * m + 0];
    float by0 = boxes[4 * m + 1];
    float bx1 = boxes[4 * m + 2];
    float by1 = boxes[4 * m + 3];

    // ---- level assignment (matches _assign_levels) ----
    float area = (bx1 - bx0) * (by1 - by0);
    float sz   = sqrtf(area);
    float lvlf = floorf(4.0f + log2f(sz / 224.0f + 1e-8f));
    lvlf = fminf(fmaxf(lvlf, 2.0f), 5.0f);
    int lvl = (int)lvlf - 2;

    const float* fp; int H; int W; float scale;
    if (lvl == 0)      { fp = f0; H = 200; W = 304; scale = 0.25f;    }
    else if (lvl == 1) { fp = f1; H = 100; W = 152; scale = 0.125f;   }
    else if (lvl == 2) { fp = f2; H = 50;  W = 76;  scale = 0.0625f;  }
    else               { fp = f3; H = 25;  W = 38;  scale = 0.03125f; }

    int b = bidx[m];
    const float* fc = fp + ((size_t)(b * NCH + c)) * (size_t)(H * W);

    // ---- box -> feature coords (matches _roi_align) ----
    float x0 = bx0 * scale - 0.5f;
    float y0 = by0 * scale - 0.5f;
    float x1 = bx1 * scale - 0.5f;
    float y1 = by1 * scale - 0.5f;
    float bin_w = (x1 - x0) * (1.0f / 7.0f);
    float bin_h = (y1 - y0) * (1.0f / 7.0f);

    float acc = 0.0f;
    #pragma unroll
    for (int sy = 0; sy < 2; ++sy) {
        // offs[s] = s//2 + (s%2 + 0.5)/2  with s = 2*py + sy
        float yy = y0 + bin_h * ((float)py + 0.25f + 0.5f * (float)sy);
        // _axis_weights on y
        float vy    = (yy >= -1.0f && yy <= (float)H) ? 1.0f : 0.0f;
        float cy    = fmaxf(yy, 0.0f);
        float ylo_f = floorf(cy);
        bool  capy  = ylo_f >= (float)(H - 1);
        int   ylo   = capy ? (H - 1) : (int)ylo_f;
        int   yhi   = capy ? (H - 1) : (ylo + 1);
        float ly    = capy ? 0.0f : (cy - ylo_f);
        float wyl   = (1.0f - ly) * vy;
        float wyh   = ly * vy;
        const float* rlo = fc + (size_t)ylo * W;
        const float* rhi = fc + (size_t)yhi * W;
        #pragma unroll
        for (int sx = 0; sx < 2; ++sx) {
            float xx = x0 + bin_w * ((float)px + 0.25f + 0.5f * (float)sx);
            // _axis_weights on x
            float vx    = (xx >= -1.0f && xx <= (float)W) ? 1.0f : 0.0f;
            float cx    = fmaxf(xx, 0.0f);
            float xlo_f = floorf(cx);
            bool  capx  = xlo_f >= (float)(W - 1);
            int   xlo   = capx ? (W - 1) : (int)xlo_f;
            int   xhi   = capx ? (W - 1) : (xlo + 1);
            float lx    = capx ? 0.0f : (cx - xlo_f);
            float wxl   = (1.0f - lx) * vx;
            float wxh   = lx * vx;
            acc += wyl * (rlo[xlo] * wxl + rlo[xhi] * wxh)
                 + wyh * (rhi[xlo] * wxl + rhi[xhi] * wxh);
        }
    }
    out[idx] = acc * 0.25f;
}

extern "C" void kernel_launch(void* const* d_in, const int* in_sizes, int n_in,
                              void* d_out, int out_size, void* d_ws, size_t ws_size,
                              hipStream_t stream) {
    const float* f0    = (const float*)d_in[0];
    const float* f1    = (const float*)d_in[1];
    const float* f2    = (const float*)d_in[2];
    const float* f3    = (const float*)d_in[3];
    const float* boxes = (const float*)d_in[4];
    const int*   bidx  = (const int*)d_in[5];
    float* out = (float*)d_out;

    int M = in_sizes[4] / 4;
    int total = M * NCH * POOL * POOL;
    int blocks = (total + 255) / 256;
    hipLaunchKernelGGL(roi_align_kernel, dim3(blocks), dim3(256), 0, stream,
                       f0, f1, f2, f3, boxes, bidx, out, M);
}